// Round 20
// baseline (206.477 us; speedup 1.0000x reference)
//
#include <hip/hip_runtime.h>
#include <hip/hip_bf16.h>

#define S_LEN 2048
#define NHEADS 8
#define DHEAD 64
#define NBATCH 4
#define DMODEL 512

typedef __attribute__((ext_vector_type(8))) short short8;
typedef __attribute__((ext_vector_type(4))) short short4v;
typedef __attribute__((ext_vector_type(4))) float f32x4;

__device__ __forceinline__ short f2bf(float f) {
    unsigned int u = __builtin_bit_cast(unsigned int, f);
    u = (u + 0x7fffu + ((u >> 16) & 1u)) >> 16;
    return (short)u;
}

// ---------------- x / W / Er f32 -> bf16, one fused launch ----------------
__global__ __launch_bounds__(256) void conv_bf16(
    const float* __restrict__ x, const float* __restrict__ Wq,
    const float* __restrict__ Wk, const float* __restrict__ Wv,
    const float* __restrict__ er,
    unsigned short* __restrict__ xb, unsigned short* __restrict__ wb,
    unsigned short* __restrict__ erb)
{
    const int bid = blockIdx.x;
    const float* src;
    unsigned short* dst;
    int idx;
    if (bid < 4096) {                       // x: 4096 blocks x 1024 f32
        src = x; dst = xb; idx = bid * 256 + threadIdx.x;
    } else if (bid < 4864) {                // W: 256 blocks each
        const int m = (bid - 4096) >> 8;
        src = (m == 0) ? Wq : (m == 1) ? Wk : Wv;
        dst = wb + m * (DMODEL * DMODEL);
        idx = ((bid - 4096) & 255) * 256 + threadIdx.x;
    } else {                                // Er: 128 blocks
        src = er; dst = erb;
        idx = (bid - 4864) * 256 + threadIdx.x;
    }
    float4 v = *(const float4*)(src + idx * 4);
    short4v s;
    s[0] = f2bf(v.x); s[1] = f2bf(v.y); s[2] = f2bf(v.z); s[3] = f2bf(v.w);
    *(short4v*)(dst + idx * 4) = s;
}

// ---------------- QKV projection: y[m,n] = sum_k x[m,k]*W[n,k] + b[n] ----------------
// Inputs PRE-CONVERTED bf16 (xb, wb). Q,K out in [mat][b][h][s][dh];
// V TRANSPOSED [b][h][dh][s]. Q pre-scaled by 1/(8*ln2).
__global__ __launch_bounds__(256) void qkv_gemm(
    const unsigned short* __restrict__ xb,
    const unsigned short* __restrict__ wb,
    const float* __restrict__ bq, const float* __restrict__ bk,
    const float* __restrict__ bv,
    unsigned short* __restrict__ qkv)
{
    __shared__ __align__(16) short smem[64 * 136];   // xt(128*40) + wt(64*40); reused for V transpose
    short* xt = smem;
    short* wt = smem + 128 * 40;
    const int tid = threadIdx.x;
    const int w = tid >> 6;
    const int l = tid & 63;
    const int lrow = l & 15, lgrp = l >> 4;
    const int m0 = blockIdx.x * 128;
    const int nb = blockIdx.y;
    const int mat = nb >> 3, hh = nb & 7;
    const unsigned short* wmat = wb + mat * (DMODEL * DMODEL);
    const float* bias = (mat == 0) ? bq : ((mat == 1) ? bk : bv);
    const int n0 = hh * 64;

    f32x4 acc[2][4];
    #pragma unroll
    for (int i = 0; i < 2; i++)
        #pragma unroll
        for (int j = 0; j < 4; j++) acc[i][j] = (f32x4)0.0f;

    const int xur = tid >> 2, xus = tid & 3;
    const int wur = tid >> 2, wus = tid & 3;

    for (int k0 = 0; k0 < DMODEL; k0 += 32) {
        short8 xa0 = *(const short8*)(xb + (size_t)(m0 + xur) * DMODEL + k0 + xus * 8);
        short8 xa1 = *(const short8*)(xb + (size_t)(m0 + xur + 64) * DMODEL + k0 + xus * 8);
        short8 wa  = *(const short8*)(wmat + (size_t)(n0 + wur) * DMODEL + k0 + wus * 8);
        *(short8*)(xt + xur * 40 + xus * 8)        = xa0;
        *(short8*)(xt + (xur + 64) * 40 + xus * 8) = xa1;
        *(short8*)(wt + wur * 40 + wus * 8)        = wa;
        __syncthreads();
        #pragma unroll
        for (int nc = 0; nc < 4; nc++) {
            short8 bfrag = *(const short8*)(wt + (nc * 16 + lrow) * 40 + lgrp * 8);
            #pragma unroll
            for (int mf = 0; mf < 2; mf++) {
                short8 afrag = *(const short8*)(xt + (w * 32 + mf * 16 + lrow) * 40 + lgrp * 8);
                acc[mf][nc] = __builtin_amdgcn_mfma_f32_16x16x32_bf16(afrag, bfrag, acc[mf][nc], 0, 0, 0);
            }
        }
        __syncthreads();
    }

    const int b  = m0 >> 11;
    const int s0 = m0 & (S_LEN - 1);
    if (mat == 2) {
        short* vl = smem;   // 64 x 136 shorts
        #pragma unroll
        for (int nc = 0; nc < 4; nc++) {
            const int d = nc * 16 + lrow;
            const float bias_v = bias[n0 + d];
            #pragma unroll
            for (int mf = 0; mf < 2; mf++)
                #pragma unroll
                for (int r = 0; r < 4; r++) {
                    const int sl = w * 32 + mf * 16 + lgrp * 4 + r;
                    vl[d * 136 + sl] = f2bf(acc[mf][nc][r] + bias_v);
                }
        }
        __syncthreads();
        unsigned short* ob = qkv + (((size_t)2 * NBATCH + b) * NHEADS + hh) * S_LEN * DHEAD;
        #pragma unroll
        for (int kch = 0; kch < 4; kch++) {
            const int c = kch * 256 + tid;
            const int d = c >> 4, seg = c & 15;
            short8 ch = *(const short8*)(vl + d * 136 + seg * 8);
            *(short8*)(ob + (size_t)d * S_LEN + s0 + seg * 8) = ch;
        }
    } else {
        const float oscale = (mat == 0) ? 0.18033688f : 1.0f;   // Q: 1/(8*ln2)
        unsigned short* ob = qkv + (((size_t)mat * NBATCH + b) * NHEADS + hh) * S_LEN * DHEAD;
        #pragma unroll
        for (int nc = 0; nc < 4; nc++) {
            const int d = nc * 16 + lrow;
            const float bias_v = bias[n0 + d];
            #pragma unroll
            for (int mf = 0; mf < 2; mf++) {
                #pragma unroll
                for (int r = 0; r < 4; r++) {
                    int srow = s0 + w * 32 + mf * 16 + lgrp * 4 + r;
                    ob[(size_t)srow * DHEAD + d] =
                        (unsigned short)f2bf((acc[mf][nc][r] + bias_v) * oscale);
                }
            }
        }
    }
}

// ---------------- fused causal attention with relative (skew) bias ----------------
// P = exp2(q'.k[t] + q'.Er[t-s+S-1]), t <= s (scale folded into Q).
// R17 body (best: 101.5us) with KVBLK=128: stage 128 t-rows of K and V per
// barrier, run the proven 64-wide compute TWICE between barriers. Barriers
// 33->17 per strip-pair; the two halves are independent (2x ILP per wave
// between syncs); K/V prefetch distance doubles. Er prefetch stays at
// 64-half granularity. LDS 75KB -> still 2 blocks/CU.
__global__ __launch_bounds__(256) void rga_attn(
    const unsigned short* __restrict__ qkv,
    const unsigned short* __restrict__ er,
    float* __restrict__ out)
{
    __shared__ __align__(16) unsigned short klds[2][128 * 64];  // [t][d], rows 128B xor-swizzled
    __shared__ __align__(16) unsigned short vt[2][64 * 136];    // [d][t], stride 136 (pad)
    __shared__ __align__(16) unsigned short plds[4][16 * 64];   // per-wave P, rows 128B xor-swizzled

    const int tid = threadIdx.x;
    const int w = tid >> 6;
    const int l = tid & 63;
    const int lrow = l & 15, lgrp = l >> 4;
    const int p  = blockIdx.x;         // pair id 0..15
    const int bh = blockIdx.y;
    const int b = bh >> 3, hh = bh & 7;

    const unsigned short* qp  = qkv + (size_t)bh * S_LEN * DHEAD;
    const unsigned short* kp  = qkv + ((size_t)(NBATCH * NHEADS) + bh) * S_LEN * DHEAD;
    const unsigned short* vtg = qkv + ((size_t)(2 * NBATCH * NHEADS) + bh) * S_LEN * DHEAD;

    short8 ones;
    #pragma unroll
    for (int e = 0; e < 8; e++) ones[e] = (short)0x3F80;   // bf16 1.0

    // K staging: 128 rows x 8 short8/row = 1024 units; thread j: row ktr+32j
    const int ktr = tid >> 3, kseg = tid & 7;
    // V staging: 64 d-rows x 16 short8/row = 1024 units; thread j: d vdr+16j
    const int vdr = tid >> 4, vseg = tid & 15;
    unsigned short* pw = plds[w];

    #pragma unroll 1
    for (int sp = 0; sp < 2; sp++) {
        const int sid = sp ? p : (31 - p);     // heavy strip first
        const int q0 = sid * 64;
        const int s_base = q0 + w * 16;
        const int nt64 = sid + 1;
        const int nt = (nt64 + 1) >> 1;        // 128-t tiles

        short8 aq[2];
        {
            const unsigned short* qr = qp + (size_t)(s_base + lrow) * DHEAD + lgrp * 8;
            aq[0] = *(const short8*)(qr);
            aq[1] = *(const short8*)(qr + 32);
        }

        f32x4 o[4], lsum;
        lsum = (f32x4)0.0f;
        #pragma unroll
        for (int n = 0; n < 4; n++) o[n] = (f32x4)0.0f;

        // ---- prologue: stage 128-tile 0, prefetch tile 1, Er half 0 ----
        short8 kreg[4], vreg[4], ereg0[5], ereg1[5];
        #pragma unroll
        for (int j = 0; j < 4; j++) {
            kreg[j] = *(const short8*)(kp + (size_t)(ktr + 32 * j) * DHEAD + kseg * 8);
            vreg[j] = *(const short8*)(vtg + (size_t)(vdr + 16 * j) * S_LEN + vseg * 8);
        }
        #pragma unroll
        for (int j = 0; j < 4; j++) {
            const int tr = ktr + 32 * j;
            *(short8*)((char*)klds[0] + tr * 128 + ((kseg * 16) ^ ((tr & 7) << 4))) = kreg[j];
            *(short8*)(vt[0] + (vdr + 16 * j) * 136 + vseg * 8) = vreg[j];
        }
        if (nt > 1) {
            #pragma unroll
            for (int j = 0; j < 4; j++) {
                kreg[j] = *(const short8*)(kp + (size_t)(128 + ktr + 32 * j) * DHEAD + kseg * 8);
                vreg[j] = *(const short8*)(vtg + (size_t)(vdr + 16 * j) * S_LEN + 128 + vseg * 8);
            }
        }
        {
            const int r_lo = -s_base + (S_LEN - 16);
            #pragma unroll
            for (int f = 0; f < 5; f++) {
                int rr = r_lo + f * 16 + lrow;
                rr = rr < 0 ? 0 : (rr > (S_LEN - 1) ? (S_LEN - 1) : rr);
                const unsigned short* ep = er + (size_t)rr * DHEAD + lgrp * 8;
                ereg0[f] = *(const short8*)(ep);
                ereg1[f] = *(const short8*)(ep + 32);
            }
        }
        __syncthreads();   // tile-0 staging visible to all waves

        for (int it = 0; it < nt; it++) {
            const int t0 = it << 7;
            const int cur = it & 1;
            // ---- write prefetched 128-tile it+1 into the other buffer ----
            if (it + 1 < nt) {
                unsigned short* kd = klds[cur ^ 1];
                unsigned short* vd = vt[cur ^ 1];
                #pragma unroll
                for (int j = 0; j < 4; j++) {
                    const int tr = ktr + 32 * j;
                    *(short8*)((char*)kd + tr * 128 + ((kseg * 16) ^ ((tr & 7) << 4))) = kreg[j];
                    *(short8*)(vd + (vdr + 16 * j) * 136 + vseg * 8) = vreg[j];
                }
            }
            #pragma unroll 1
            for (int h = 0; h < 2; h++) {
                const int i64 = it * 2 + h;
                if (i64 >= nt64) break;
                const int th0 = t0 + (h << 6);
                // ---- QEr band (prefetched regs): 5 frags, jr in [0,79] ----
                f32x4 qe[5];
                __builtin_amdgcn_s_setprio(1);
                #pragma unroll
                for (int f = 0; f < 5; f++) {
                    f32x4 a = (f32x4)0.0f;
                    a = __builtin_amdgcn_mfma_f32_16x16x32_bf16(aq[0], ereg0[f], a, 0, 0, 0);
                    a = __builtin_amdgcn_mfma_f32_16x16x32_bf16(aq[1], ereg1[f], a, 0, 0, 0);
                    qe[f] = a;
                }
                __builtin_amdgcn_s_setprio(0);
                // ---- issue loads: K/V for 128-tile it+2 (during half 0) ----
                if (h == 0 && it + 2 < nt) {
                    const int tn = t0 + 256;
                    #pragma unroll
                    for (int j = 0; j < 4; j++) {
                        kreg[j] = *(const short8*)(kp + (size_t)(tn + ktr + 32 * j) * DHEAD + kseg * 8);
                        vreg[j] = *(const short8*)(vtg + (size_t)(vdr + 16 * j) * S_LEN + tn + vseg * 8);
                    }
                }
                // ---- Er for next 64-half ----
                if (i64 + 1 < nt64) {
                    const int thn = th0 + 64;
                    const int r_lo = thn - s_base + (S_LEN - 16);
                    if (thn + 64 <= s_base) {   // next half below diagonal: no clamp
                        #pragma unroll
                        for (int f = 0; f < 5; f++) {
                            const unsigned short* ep = er + (size_t)(r_lo + f * 16 + lrow) * DHEAD + lgrp * 8;
                            ereg0[f] = *(const short8*)(ep);
                            ereg1[f] = *(const short8*)(ep + 32);
                        }
                    } else {
                        #pragma unroll
                        for (int f = 0; f < 5; f++) {
                            int rr = r_lo + f * 16 + lrow;
                            rr = rr < 0 ? 0 : (rr > (S_LEN - 1) ? (S_LEN - 1) : rr);
                            const unsigned short* ep = er + (size_t)rr * DHEAD + lgrp * 8;
                            ereg0[f] = *(const short8*)(ep);
                            ereg1[f] = *(const short8*)(ep + 32);
                        }
                    }
                }
                // ---- QK^T: 16 rows x 64 t from klds[cur], row base h*64 ----
                f32x4 sfr[4];
                __builtin_amdgcn_s_setprio(1);
                #pragma unroll
                for (int u = 0; u < 4; u++) {
                    const int trow = (h << 6) + u * 16 + lrow;
                    const char* kb = (const char*)klds[cur] + trow * 128;
                    const int swz = (trow & 7) << 4;
                    short8 kb0 = *(const short8*)(kb + ((lgrp * 16) ^ swz));
                    short8 kb1 = *(const short8*)(kb + ((64 + lgrp * 16) ^ swz));
                    f32x4 a = (f32x4)0.0f;
                    a = __builtin_amdgcn_mfma_f32_16x16x32_bf16(aq[0], kb0, a, 0, 0, 0);
                    a = __builtin_amdgcn_mfma_f32_16x16x32_bf16(aq[1], kb1, a, 0, 0, 0);
                    sfr[u] = a;
                }
                __builtin_amdgcn_s_setprio(0);
                // ---- band gather + exp2 + cvt_pk pack -> LDS ----
                if (th0 + 64 <= s_base) {
                    // FAST PATH: fully below diagonal -- no mask needed
                    #pragma unroll
                    for (int r = 0; r < 4; r++) {
                        const int si = lgrp * 4 + r;
                        const int dd = lrow - si + 15;            // [0,30]
                        const int srcl = (l & 48) | (dd & 15);
                        const int hi = dd >> 4;
                        float sh[5];
                        #pragma unroll
                        for (int f = 0; f < 5; f++) sh[f] = __shfl(qe[f][r], srcl);
                        const int pswz = (si & 7) << 4;
                        char* pr = (char*)pw + si * 128;
                        float pe[4];
                        #pragma unroll
                        for (int u = 0; u < 4; u++) {
                            const float rel = hi ? sh[u + 1] : sh[u];
                            float sc = sfr[u][r] + rel;
                            asm("v_exp_f32 %0, %1\ns_nop 1" : "=v"(pe[u]) : "v"(sc));
                        }
                        #pragma unroll
                        for (int h2 = 0; h2 < 2; h2++) {
                            unsigned pk;
                            asm("v_cvt_pk_bf16_f32 %0, %1, %2"
                                : "=v"(pk) : "v"(pe[h2 * 2]), "v"(pe[h2 * 2 + 1]));
                            *(unsigned short*)(pr + (((h2 * 32 + lrow) * 2) ^ pswz)) = (unsigned short)pk;
                            *(unsigned short*)(pr + (((h2 * 32 + 16 + lrow) * 2) ^ pswz)) = (unsigned short)(pk >> 16);
                        }
                    }
                } else {
                    // EDGE PATH: diagonal half -- mask + full handling
                    #pragma unroll
                    for (int r = 0; r < 4; r++) {
                        const int si = lgrp * 4 + r;
                        const int sg = s_base + si;
                        const int dd = lrow - si + 15;            // [0,30]
                        const int srcl = (l & 48) | (dd & 15);
                        const int hi = dd >> 4;
                        float sh[5];
                        #pragma unroll
                        for (int f = 0; f < 5; f++) sh[f] = __shfl(qe[f][r], srcl);
                        const int pswz = (si & 7) << 4;
                        char* pr = (char*)pw + si * 128;
                        float pe[4];
                        #pragma unroll
                        for (int u = 0; u < 4; u++) {
                            const float rel = hi ? sh[u + 1] : sh[u];
                            float sc = sfr[u][r] + rel;
                            float ex;
                            asm("v_exp_f32 %0, %1\ns_nop 1" : "=v"(ex) : "v"(sc));
                            pe[u] = ((th0 + u * 16 + lrow) <= sg) ? ex : 0.0f;
                        }
                        #pragma unroll
                        for (int h2 = 0; h2 < 2; h2++) {
                            unsigned pk;
                            asm("v_cvt_pk_bf16_f32 %0, %1, %2"
                                : "=v"(pk) : "v"(pe[h2 * 2]), "v"(pe[h2 * 2 + 1]));
                            *(unsigned short*)(pr + (((h2 * 32 + lrow) * 2) ^ pswz)) = (unsigned short)pk;
                            *(unsigned short*)(pr + (((h2 * 32 + 16 + lrow) * 2) ^ pswz)) = (unsigned short)(pk >> 16);
                        }
                    }
                }
                asm volatile("s_waitcnt lgkmcnt(0)" ::: "memory");
                __builtin_amdgcn_sched_barrier(0);
                // ---- PV + row-sum (denominator) from vt[cur], col base h*64 ----
                __builtin_amdgcn_s_setprio(1);
                const int pswz2 = (lrow & 7) << 4;
                #pragma unroll
                for (int kk = 0; kk < 2; kk++) {
                    short8 pa = *(const short8*)((const char*)pw + lrow * 128 +
                                                 ((kk * 64 + lgrp * 16) ^ pswz2));
                    lsum = __builtin_amdgcn_mfma_f32_16x16x32_bf16(pa, ones, lsum, 0, 0, 0);
                    #pragma unroll
                    for (int n = 0; n < 4; n++) {
                        short8 vb = *(const short8*)(vt[cur] + (n * 16 + lrow) * 136 +
                                                     (h << 6) + kk * 32 + lgrp * 8);
                        o[n] = __builtin_amdgcn_mfma_f32_16x16x32_bf16(pa, vb, o[n], 0, 0, 0);
                    }
                }
                __builtin_amdgcn_s_setprio(0);
            }
            __syncthreads();   // the ONE barrier per 128-tile
        }

        #pragma unroll
        for (int r = 0; r < 4; r++) {
            const int sg = s_base + lgrp * 4 + r;
            const float inv = 1.0f / lsum[r];
            float* orow = out + ((size_t)b * S_LEN + sg) * DMODEL + hh * DHEAD;
            #pragma unroll
            for (int n = 0; n < 4; n++)
                orow[n * 16 + lrow] = o[n][r] * inv;
        }
    }
}

extern "C" void kernel_launch(void* const* d_in, const int* in_sizes, int n_in,
                              void* d_out, int out_size, void* d_ws, size_t ws_size,
                              hipStream_t stream) {
    const float* x  = (const float*)d_in[0];
    const float* Wq = (const float*)d_in[1];
    const float* bq = (const float*)d_in[2];
    const float* Wk = (const float*)d_in[3];
    const float* bk = (const float*)d_in[4];
    const float* Wv = (const float*)d_in[5];
    const float* bv = (const float*)d_in[6];
    const float* Er = (const float*)d_in[7];

    unsigned short* ws_qkv = (unsigned short*)d_ws;                       // Q,K [b][h][s][d]; V^T [b][h][d][s]
    unsigned short* ws_er  = ws_qkv + (size_t)3 * NBATCH * NHEADS * S_LEN * DHEAD;

    // xb/wb live in d_out (16.8MB): dead until rga_attn's final write, which
    // runs strictly after qkv_gemm on the stream. xb 8.4MB + wb 1.5MB.
    unsigned short* xb = (unsigned short*)d_out;
    unsigned short* wb = xb + (size_t)NBATCH * S_LEN * DMODEL;

    conv_bf16<<<dim3(4096 + 3 * 256 + 128), dim3(256), 0, stream>>>(x, Wq, Wk, Wv, Er, xb, wb, ws_er);
    qkv_gemm<<<dim3(64, 24), dim3(256), 0, stream>>>(xb, wb, bq, bk, bv, ws_qkv);
    rga_attn<<<dim3(16, 32), dim3(256), 0, stream>>>(ws_qkv, ws_er, (float*)d_out);
}

// Round 21
// 127.171 us; speedup vs baseline: 1.6236x; 1.6236x over previous
//
#include <hip/hip_runtime.h>
#include <hip/hip_bf16.h>

#define S_LEN 2048
#define NHEADS 8
#define DHEAD 64
#define NBATCH 4
#define DMODEL 512

typedef __attribute__((ext_vector_type(8))) short short8;
typedef __attribute__((ext_vector_type(4))) short short4v;
typedef __attribute__((ext_vector_type(4))) float f32x4;

__device__ __forceinline__ short f2bf(float f) {
    unsigned int u = __builtin_bit_cast(unsigned int, f);
    u = (u + 0x7fffu + ((u >> 16) & 1u)) >> 16;
    return (short)u;
}

// ---------------- x / W / Er f32 -> bf16, one fused launch ----------------
__global__ __launch_bounds__(256) void conv_bf16(
    const float* __restrict__ x, const float* __restrict__ Wq,
    const float* __restrict__ Wk, const float* __restrict__ Wv,
    const float* __restrict__ er,
    unsigned short* __restrict__ xb, unsigned short* __restrict__ wb,
    unsigned short* __restrict__ erb)
{
    const int bid = blockIdx.x;
    const float* src;
    unsigned short* dst;
    int idx;
    if (bid < 4096) {                       // x: 4096 blocks x 1024 f32
        src = x; dst = xb; idx = bid * 256 + threadIdx.x;
    } else if (bid < 4864) {                // W: 256 blocks each
        const int m = (bid - 4096) >> 8;
        src = (m == 0) ? Wq : (m == 1) ? Wk : Wv;
        dst = wb + m * (DMODEL * DMODEL);
        idx = ((bid - 4096) & 255) * 256 + threadIdx.x;
    } else {                                // Er: 128 blocks
        src = er; dst = erb;
        idx = (bid - 4864) * 256 + threadIdx.x;
    }
    float4 v = *(const float4*)(src + idx * 4);
    short4v s;
    s[0] = f2bf(v.x); s[1] = f2bf(v.y); s[2] = f2bf(v.z); s[3] = f2bf(v.w);
    *(short4v*)(dst + idx * 4) = s;
}

// ---------------- QKV projection: y[m,n] = sum_k x[m,k]*W[n,k] + b[n] ----------------
// Inputs PRE-CONVERTED bf16 (xb, wb). Q,K out in [mat][b][h][s][dh];
// V TRANSPOSED [b][h][dh][s]. Q pre-scaled by 1/(8*ln2).
__global__ __launch_bounds__(256) void qkv_gemm(
    const unsigned short* __restrict__ xb,
    const unsigned short* __restrict__ wb,
    const float* __restrict__ bq, const float* __restrict__ bk,
    const float* __restrict__ bv,
    unsigned short* __restrict__ qkv)
{
    __shared__ __align__(16) short smem[64 * 136];   // xt(128*40) + wt(64*40); reused for V transpose
    short* xt = smem;
    short* wt = smem + 128 * 40;
    const int tid = threadIdx.x;
    const int w = tid >> 6;
    const int l = tid & 63;
    const int lrow = l & 15, lgrp = l >> 4;
    const int m0 = blockIdx.x * 128;
    const int nb = blockIdx.y;
    const int mat = nb >> 3, hh = nb & 7;
    const unsigned short* wmat = wb + mat * (DMODEL * DMODEL);
    const float* bias = (mat == 0) ? bq : ((mat == 1) ? bk : bv);
    const int n0 = hh * 64;

    f32x4 acc[2][4];
    #pragma unroll
    for (int i = 0; i < 2; i++)
        #pragma unroll
        for (int j = 0; j < 4; j++) acc[i][j] = (f32x4)0.0f;

    const int xur = tid >> 2, xus = tid & 3;
    const int wur = tid >> 2, wus = tid & 3;

    for (int k0 = 0; k0 < DMODEL; k0 += 32) {
        short8 xa0 = *(const short8*)(xb + (size_t)(m0 + xur) * DMODEL + k0 + xus * 8);
        short8 xa1 = *(const short8*)(xb + (size_t)(m0 + xur + 64) * DMODEL + k0 + xus * 8);
        short8 wa  = *(const short8*)(wmat + (size_t)(n0 + wur) * DMODEL + k0 + wus * 8);
        *(short8*)(xt + xur * 40 + xus * 8)        = xa0;
        *(short8*)(xt + (xur + 64) * 40 + xus * 8) = xa1;
        *(short8*)(wt + wur * 40 + wus * 8)        = wa;
        __syncthreads();
        #pragma unroll
        for (int nc = 0; nc < 4; nc++) {
            short8 bfrag = *(const short8*)(wt + (nc * 16 + lrow) * 40 + lgrp * 8);
            #pragma unroll
            for (int mf = 0; mf < 2; mf++) {
                short8 afrag = *(const short8*)(xt + (w * 32 + mf * 16 + lrow) * 40 + lgrp * 8);
                acc[mf][nc] = __builtin_amdgcn_mfma_f32_16x16x32_bf16(afrag, bfrag, acc[mf][nc], 0, 0, 0);
            }
        }
        __syncthreads();
    }

    const int b  = m0 >> 11;
    const int s0 = m0 & (S_LEN - 1);
    if (mat == 2) {
        short* vl = smem;   // 64 x 136 shorts
        #pragma unroll
        for (int nc = 0; nc < 4; nc++) {
            const int d = nc * 16 + lrow;
            const float bias_v = bias[n0 + d];
            #pragma unroll
            for (int mf = 0; mf < 2; mf++)
                #pragma unroll
                for (int r = 0; r < 4; r++) {
                    const int sl = w * 32 + mf * 16 + lgrp * 4 + r;
                    vl[d * 136 + sl] = f2bf(acc[mf][nc][r] + bias_v);
                }
        }
        __syncthreads();
        unsigned short* ob = qkv + (((size_t)2 * NBATCH + b) * NHEADS + hh) * S_LEN * DHEAD;
        #pragma unroll
        for (int kch = 0; kch < 4; kch++) {
            const int c = kch * 256 + tid;
            const int d = c >> 4, seg = c & 15;
            short8 ch = *(const short8*)(vl + d * 136 + seg * 8);
            *(short8*)(ob + (size_t)d * S_LEN + s0 + seg * 8) = ch;
        }
    } else {
        const float oscale = (mat == 0) ? 0.18033688f : 1.0f;   // Q: 1/(8*ln2)
        unsigned short* ob = qkv + (((size_t)mat * NBATCH + b) * NHEADS + hh) * S_LEN * DHEAD;
        #pragma unroll
        for (int nc = 0; nc < 4; nc++) {
            const int d = nc * 16 + lrow;
            const float bias_v = bias[n0 + d];
            #pragma unroll
            for (int mf = 0; mf < 2; mf++) {
                #pragma unroll
                for (int r = 0; r < 4; r++) {
                    int srow = s0 + w * 32 + mf * 16 + lgrp * 4 + r;
                    ob[(size_t)srow * DHEAD + d] =
                        (unsigned short)f2bf((acc[mf][nc][r] + bias_v) * oscale);
                }
            }
        }
    }
}

// ---------------- fused causal attention with relative (skew) bias ----------------
// P = exp2(q'.k[t] + q'.Er[t-s+S-1]), t <= s (scale folded into Q).
// FINAL (R17 configuration -- best of 20 rounds, rga_attn ~101.5us):
// 512 uniform paired blocks (strips 31-p then p = exactly 33 tiles/block,
// zero tail imbalance), 4-wave 64-row strips sharing K/V LDS tiles,
// double-buffered K/V + 2-deep reg prefetch, SINGLE barrier/tile,
// Er reg-prefetch one tile ahead, diagonal fast-path (mask/clamp elided on
// 32 of 33 tiles), v_exp_f32 + cvt_pk softmax, per-wave swizzled P bounce.
// Perturbations all regress: 2-wave blocks (R16 +51%), 3 blocks/CU (R18
// +38%), V-hoist/fence-removal (R19 +20%), KVBLK=128 (R20 +77%).
__global__ __launch_bounds__(256) void rga_attn(
    const unsigned short* __restrict__ qkv,
    const unsigned short* __restrict__ er,
    float* __restrict__ out)
{
    __shared__ __align__(16) unsigned short klds[2][64 * 64];   // [t][d], rows 128B xor-swizzled
    __shared__ __align__(16) unsigned short vt[2][64 * 72];     // [d][t], stride 72 (pad)
    __shared__ __align__(16) unsigned short plds[4][16 * 64];   // per-wave P, rows 128B xor-swizzled

    const int tid = threadIdx.x;
    const int w = tid >> 6;
    const int l = tid & 63;
    const int lrow = l & 15, lgrp = l >> 4;
    const int p  = blockIdx.x;         // pair id 0..15
    const int bh = blockIdx.y;
    const int b = bh >> 3, hh = bh & 7;

    const unsigned short* qp  = qkv + (size_t)bh * S_LEN * DHEAD;
    const unsigned short* kp  = qkv + ((size_t)(NBATCH * NHEADS) + bh) * S_LEN * DHEAD;
    const unsigned short* vtg = qkv + ((size_t)(2 * NBATCH * NHEADS) + bh) * S_LEN * DHEAD;

    short8 ones;
    #pragma unroll
    for (int e = 0; e < 8; e++) ones[e] = (short)0x3F80;   // bf16 1.0

    const int tr0 = tid >> 3, tr1 = (tid >> 3) + 32, seg = tid & 7;
    unsigned short* pw = plds[w];

    #pragma unroll 1
    for (int sp = 0; sp < 2; sp++) {
        const int sid = sp ? p : (31 - p);     // heavy strip first
        const int q0 = sid * 64;
        const int s_base = q0 + w * 16;
        const int nt = sid + 1;

        short8 aq[2];
        {
            const unsigned short* qr = qp + (size_t)(s_base + lrow) * DHEAD + lgrp * 8;
            aq[0] = *(const short8*)(qr);
            aq[1] = *(const short8*)(qr + 32);
        }

        f32x4 o[4], lsum;
        lsum = (f32x4)0.0f;
        #pragma unroll
        for (int n = 0; n < 4; n++) o[n] = (f32x4)0.0f;

        // ---- prologue: stage tile 0, prefetch tile 1, Er tile 0 ----
        short8 kreg[2], vreg[2], ereg0[5], ereg1[5];
        kreg[0] = *(const short8*)(kp + (size_t)tr0 * DHEAD + seg * 8);
        kreg[1] = *(const short8*)(kp + (size_t)tr1 * DHEAD + seg * 8);
        vreg[0] = *(const short8*)(vtg + (size_t)tr0 * S_LEN + seg * 8);
        vreg[1] = *(const short8*)(vtg + (size_t)tr1 * S_LEN + seg * 8);
        *(short8*)((char*)klds[0] + tr0 * 128 + ((seg * 16) ^ ((tr0 & 7) << 4))) = kreg[0];
        *(short8*)((char*)klds[0] + tr1 * 128 + ((seg * 16) ^ ((tr1 & 7) << 4))) = kreg[1];
        *(short8*)(vt[0] + tr0 * 72 + seg * 8) = vreg[0];
        *(short8*)(vt[0] + tr1 * 72 + seg * 8) = vreg[1];
        if (nt > 1) {
            kreg[0] = *(const short8*)(kp + (size_t)(64 + tr0) * DHEAD + seg * 8);
            kreg[1] = *(const short8*)(kp + (size_t)(64 + tr1) * DHEAD + seg * 8);
            vreg[0] = *(const short8*)(vtg + (size_t)tr0 * S_LEN + 64 + seg * 8);
            vreg[1] = *(const short8*)(vtg + (size_t)tr1 * S_LEN + 64 + seg * 8);
        }
        {
            const int r_lo = -s_base + (S_LEN - 16);
            #pragma unroll
            for (int f = 0; f < 5; f++) {
                int rr = r_lo + f * 16 + lrow;
                rr = rr < 0 ? 0 : (rr > (S_LEN - 1) ? (S_LEN - 1) : rr);
                const unsigned short* ep = er + (size_t)rr * DHEAD + lgrp * 8;
                ereg0[f] = *(const short8*)(ep);
                ereg1[f] = *(const short8*)(ep + 32);
            }
        }
        __syncthreads();   // tile-0 staging visible to all waves

        for (int it = 0; it < nt; it++) {
            const int t0 = it << 6;
            const int cur = it & 1;
            // ---- write prefetched tile it+1 into the other buffer ----
            if (it + 1 < nt) {
                unsigned short* kd = klds[cur ^ 1];
                unsigned short* vd = vt[cur ^ 1];
                *(short8*)((char*)kd + tr0 * 128 + ((seg * 16) ^ ((tr0 & 7) << 4))) = kreg[0];
                *(short8*)((char*)kd + tr1 * 128 + ((seg * 16) ^ ((tr1 & 7) << 4))) = kreg[1];
                *(short8*)(vd + tr0 * 72 + seg * 8) = vreg[0];
                *(short8*)(vd + tr1 * 72 + seg * 8) = vreg[1];
            }
            // ---- QEr band (prefetched regs): 5 frags cover jr in [0,79] ----
            f32x4 qe[5];
            __builtin_amdgcn_s_setprio(1);
            #pragma unroll
            for (int f = 0; f < 5; f++) {
                f32x4 a = (f32x4)0.0f;
                a = __builtin_amdgcn_mfma_f32_16x16x32_bf16(aq[0], ereg0[f], a, 0, 0, 0);
                a = __builtin_amdgcn_mfma_f32_16x16x32_bf16(aq[1], ereg1[f], a, 0, 0, 0);
                qe[f] = a;
            }
            __builtin_amdgcn_s_setprio(0);
            // ---- issue loads: K/V for tile it+2, Er for tile it+1 ----
            if (it + 2 < nt) {
                const int tn = t0 + 128;
                kreg[0] = *(const short8*)(kp + (size_t)(tn + tr0) * DHEAD + seg * 8);
                kreg[1] = *(const short8*)(kp + (size_t)(tn + tr1) * DHEAD + seg * 8);
                vreg[0] = *(const short8*)(vtg + (size_t)tr0 * S_LEN + tn + seg * 8);
                vreg[1] = *(const short8*)(vtg + (size_t)tr1 * S_LEN + tn + seg * 8);
            }
            if (it + 1 < nt) {
                const int r_lo = t0 + 64 - s_base + (S_LEN - 16);
                if (t0 + 128 <= s_base) {   // next tile also below diagonal: no clamp
                    #pragma unroll
                    for (int f = 0; f < 5; f++) {
                        const unsigned short* ep = er + (size_t)(r_lo + f * 16 + lrow) * DHEAD + lgrp * 8;
                        ereg0[f] = *(const short8*)(ep);
                        ereg1[f] = *(const short8*)(ep + 32);
                    }
                } else {
                    #pragma unroll
                    for (int f = 0; f < 5; f++) {
                        int rr = r_lo + f * 16 + lrow;
                        rr = rr < 0 ? 0 : (rr > (S_LEN - 1) ? (S_LEN - 1) : rr);
                        const unsigned short* ep = er + (size_t)rr * DHEAD + lgrp * 8;
                        ereg0[f] = *(const short8*)(ep);
                        ereg1[f] = *(const short8*)(ep + 32);
                    }
                }
            }
            // ---- QK^T: 16 rows x 64 t from buf[cur] ----
            f32x4 sfr[4];
            __builtin_amdgcn_s_setprio(1);
            #pragma unroll
            for (int u = 0; u < 4; u++) {
                const int trow = u * 16 + lrow;
                const char* kb = (const char*)klds[cur] + trow * 128;
                const int swz = (trow & 7) << 4;
                short8 kb0 = *(const short8*)(kb + ((lgrp * 16) ^ swz));
                short8 kb1 = *(const short8*)(kb + ((64 + lgrp * 16) ^ swz));
                f32x4 a = (f32x4)0.0f;
                a = __builtin_amdgcn_mfma_f32_16x16x32_bf16(aq[0], kb0, a, 0, 0, 0);
                a = __builtin_amdgcn_mfma_f32_16x16x32_bf16(aq[1], kb1, a, 0, 0, 0);
                sfr[u] = a;
            }
            __builtin_amdgcn_s_setprio(0);
            // ---- band gather + exp2 + cvt_pk pack -> LDS ----
            if (t0 + 64 <= s_base) {
                // FAST PATH: fully below diagonal -- no mask needed
                #pragma unroll
                for (int r = 0; r < 4; r++) {
                    const int si = lgrp * 4 + r;
                    const int dd = lrow - si + 15;            // [0,30]
                    const int srcl = (l & 48) | (dd & 15);
                    const int hi = dd >> 4;
                    float sh[5];
                    #pragma unroll
                    for (int f = 0; f < 5; f++) sh[f] = __shfl(qe[f][r], srcl);
                    const int pswz = (si & 7) << 4;
                    char* pr = (char*)pw + si * 128;
                    float pe[4];
                    #pragma unroll
                    for (int u = 0; u < 4; u++) {
                        const float rel = hi ? sh[u + 1] : sh[u];
                        float sc = sfr[u][r] + rel;
                        asm("v_exp_f32 %0, %1\ns_nop 1" : "=v"(pe[u]) : "v"(sc));
                    }
                    #pragma unroll
                    for (int h2 = 0; h2 < 2; h2++) {
                        unsigned pk;
                        asm("v_cvt_pk_bf16_f32 %0, %1, %2"
                            : "=v"(pk) : "v"(pe[h2 * 2]), "v"(pe[h2 * 2 + 1]));
                        *(unsigned short*)(pr + (((h2 * 32 + lrow) * 2) ^ pswz)) = (unsigned short)pk;
                        *(unsigned short*)(pr + (((h2 * 32 + 16 + lrow) * 2) ^ pswz)) = (unsigned short)(pk >> 16);
                    }
                }
            } else {
                // EDGE PATH: diagonal tile -- mask + full handling
                #pragma unroll
                for (int r = 0; r < 4; r++) {
                    const int si = lgrp * 4 + r;
                    const int sg = s_base + si;
                    const int dd = lrow - si + 15;            // [0,30]
                    const int srcl = (l & 48) | (dd & 15);
                    const int hi = dd >> 4;
                    float sh[5];
                    #pragma unroll
                    for (int f = 0; f < 5; f++) sh[f] = __shfl(qe[f][r], srcl);
                    const int pswz = (si & 7) << 4;
                    char* pr = (char*)pw + si * 128;
                    float pe[4];
                    #pragma unroll
                    for (int u = 0; u < 4; u++) {
                        const float rel = hi ? sh[u + 1] : sh[u];
                        float sc = sfr[u][r] + rel;
                        float ex;
                        asm("v_exp_f32 %0, %1\ns_nop 1" : "=v"(ex) : "v"(sc));
                        pe[u] = ((t0 + u * 16 + lrow) <= sg) ? ex : 0.0f;
                    }
                    #pragma unroll
                    for (int h2 = 0; h2 < 2; h2++) {
                        unsigned pk;
                        asm("v_cvt_pk_bf16_f32 %0, %1, %2"
                            : "=v"(pk) : "v"(pe[h2 * 2]), "v"(pe[h2 * 2 + 1]));
                        *(unsigned short*)(pr + (((h2 * 32 + lrow) * 2) ^ pswz)) = (unsigned short)pk;
                        *(unsigned short*)(pr + (((h2 * 32 + 16 + lrow) * 2) ^ pswz)) = (unsigned short)(pk >> 16);
                    }
                }
            }
            asm volatile("s_waitcnt lgkmcnt(0)" ::: "memory");
            __builtin_amdgcn_sched_barrier(0);
            // ---- PV + row-sum (denominator) from buf[cur] ----
            __builtin_amdgcn_s_setprio(1);
            const int pswz2 = (lrow & 7) << 4;
            #pragma unroll
            for (int kk = 0; kk < 2; kk++) {
                short8 pa = *(const short8*)((const char*)pw + lrow * 128 +
                                             ((kk * 64 + lgrp * 16) ^ pswz2));
                lsum = __builtin_amdgcn_mfma_f32_16x16x32_bf16(pa, ones, lsum, 0, 0, 0);
                #pragma unroll
                for (int n = 0; n < 4; n++) {
                    short8 vb = *(const short8*)(vt[cur] + (n * 16 + lrow) * 72 + kk * 32 + lgrp * 8);
                    o[n] = __builtin_amdgcn_mfma_f32_16x16x32_bf16(pa, vb, o[n], 0, 0, 0);
                }
            }
            __builtin_amdgcn_s_setprio(0);
            __syncthreads();   // the ONE barrier per tile
        }

        #pragma unroll
        for (int r = 0; r < 4; r++) {
            const int sg = s_base + lgrp * 4 + r;
            const float inv = 1.0f / lsum[r];
            float* orow = out + ((size_t)b * S_LEN + sg) * DMODEL + hh * DHEAD;
            #pragma unroll
            for (int n = 0; n < 4; n++)
                orow[n * 16 + lrow] = o[n][r] * inv;
        }
    }
}

extern "C" void kernel_launch(void* const* d_in, const int* in_sizes, int n_in,
                              void* d_out, int out_size, void* d_ws, size_t ws_size,
                              hipStream_t stream) {
    const float* x  = (const float*)d_in[0];
    const float* Wq = (const float*)d_in[1];
    const float* bq = (const float*)d_in[2];
    const float* Wk = (const float*)d_in[3];
    const float* bk = (const float*)d_in[4];
    const float* Wv = (const float*)d_in[5];
    const float* bv = (const float*)d_in[6];
    const float* Er = (const float*)d_in[7];

    unsigned short* ws_qkv = (unsigned short*)d_ws;                       // Q,K [b][h][s][d]; V^T [b][h][d][s]
    unsigned short* ws_er  = ws_qkv + (size_t)3 * NBATCH * NHEADS * S_LEN * DHEAD;

    // xb/wb live in d_out (16.8MB): dead until rga_attn's final write, which
    // runs strictly after qkv_gemm on the stream. xb 8.4MB + wb 1.5MB.
    unsigned short* xb = (unsigned short*)d_out;
    unsigned short* wb = xb + (size_t)NBATCH * S_LEN * DMODEL;

    conv_bf16<<<dim3(4096 + 3 * 256 + 128), dim3(256), 0, stream>>>(x, Wq, Wk, Wv, Er, xb, wb, ws_er);
    qkv_gemm<<<dim3(64, 24), dim3(256), 0, stream>>>(xb, wb, bq, bk, bv, ws_qkv);
    rga_attn<<<dim3(16, 32), dim3(256), 0, stream>>>(ws_qkv, ws_er, (float*)d_out);
}